// Round 5
// baseline (15906.238 us; speedup 1.0000x reference)
//
#include <hip/hip_runtime.h>
#include <math.h>

#define NB 512
#define TT 256
#define II 128
#define HH 1024
#define OO 128
#define TD 128
#define KC 64
#define NCHV 18         // (II+HH)/KC
#define KW (II + HH)    // 1152

typedef __attribute__((ext_vector_type(8))) short bf16x8;
typedef __attribute__((ext_vector_type(4))) float f32x4;

__device__ __forceinline__ unsigned short f2bf(float x) {
    union { float f; unsigned u; } un; un.f = x;
    unsigned r = un.u + 0x7fffu + ((un.u >> 16) & 1u);  // RN-even
    return (unsigned short)(r >> 16);
}
__device__ __forceinline__ float bf2f(unsigned short h) {
    union { unsigned u; float f; } un; un.u = ((unsigned)h) << 16; return un.f;
}
__device__ __forceinline__ float sig_(float x) { return 1.0f / (1.0f + expf(-x)); }

__device__ __forceinline__ void gl_lds16(const void* g, void* l) {
    __builtin_amdgcn_global_load_lds(
        (const __attribute__((address_space(1))) unsigned int*)g,
        (__attribute__((address_space(3))) unsigned int*)l, 16, 0, 0);
}

// One LSTM step. gates[b][n'] = sum_k A[b][k] * W'[n'][k], n' = j*4+g (gate-interleaved).
// A = [x (fp32, reg-split) | h (bf16 hi/lo)], K = 1152, 3-term hi/lo MFMA (hh, hl, lh).
// Grid 512 blocks (8 batch x 64 n-tiles, XCD-chunked), 128 thr = 2 waves, each wave
// tile 64x32 (4 m-frags x 2 n-frags). Block tile 64x64, KC=64 double-buffered
// (2 x 32KB LDS), 2 blocks/CU. LDS row = 256B = 16 slots x 16B; slot 2u = hi octet u,
// 2u+1 = lo octet u; stored slot = logical ^ (row & 15) -> conflict-free ds_read_b128.
__global__ __launch_bounds__(128)
void lstm_step_mfma(const float* __restrict__ x, long long xstride,
                    const unsigned short* __restrict__ Whi,
                    const unsigned short* __restrict__ Wlo,
                    const float* __restrict__ bsum,
                    const unsigned short* __restrict__ Hhi_in,
                    const unsigned short* __restrict__ Hlo_in,
                    unsigned short* __restrict__ Hhi_out,
                    unsigned short* __restrict__ Hlo_out,
                    float* __restrict__ h32, int write_h32,
                    float* __restrict__ cst)
{
    __shared__ __align__(16) unsigned char smem[65536];  // 2 buffers x (A 16KB + B 16KB)

    const int tid = threadIdx.x;
    const int id  = blockIdx.x;
    const int xcd = id & 7;                 // hw round-robin -> XCD
    const int rest = id >> 3;
    const int nb  = rest & 7;
    const int bb  = rest >> 3;
    const int bBase = bb * 64;
    const int nBase = (xcd * 8 + nb) * 64;  // XCD's W slice (8 n-tiles) L2-resident

    const int l  = tid & 63;
    const int w  = tid >> 6;                // wave 0..1 (n-split)
    const int lr = l & 15;
    const int lg = l >> 4;                  // k-octet within 32-k subtile

    // ds_read byte offsets
    int a_off[4][2][2];                     // [mi][ks][hi/lo]
    int b_off[2][2][2];                     // [ni][ks][hi/lo]
    #pragma unroll
    for (int ks = 0; ks < 2; ++ks)
        #pragma unroll
        for (int h = 0; h < 2; ++h) {
            const int ls = 2 * (ks * 4 + lg) + h;
            #pragma unroll
            for (int mi = 0; mi < 4; ++mi) {
                const int arow = mi * 16 + lr;
                a_off[mi][ks][h] = arow * 256 + ((ls ^ (arow & 15)) * 16);
            }
            #pragma unroll
            for (int ni = 0; ni < 2; ++ni) {
                const int brow = w * 32 + ni * 16 + lr;
                b_off[ni][ks][h] = 16384 + brow * 256 + ((ls ^ (brow & 15)) * 16);
            }
        }

    // gl_lds16 decode: instr p writes 1KB = 4 rows x 256B; lane l -> row p*4+(l>>4),
    // stored slot l&15; logical slot = (l&15) ^ (row&15)
    const int srow4 = l >> 4;
    const int sslot = l & 15;

    f32x4 acc[4][2];
    #pragma unroll
    for (int mi = 0; mi < 4; ++mi)
        #pragma unroll
        for (int ni = 0; ni < 2; ++ni)
            acc[mi][ni] = (f32x4){0.f, 0.f, 0.f, 0.f};

    auto stage = [&](int cc, int buf) {
        const unsigned bufb = (unsigned)buf * 32768u;
        const int k0 = cc * KC;
        // B from W' (8 gl_lds16 per wave, 16 per block covering 64 rows)
        #pragma unroll
        for (int i = 0; i < 8; ++i) {
            const int p = w * 8 + i;
            const int r = p * 4 + srow4;
            const int ls = sslot ^ (r & 15);
            const unsigned short* base = (ls & 1) ? Wlo : Whi;
            gl_lds16(base + (size_t)(nBase + r) * KW + k0 + (ls >> 1) * 8,
                     &smem[bufb + 16384u + (unsigned)p * 1024u]);
        }
        if (k0 >= II) {
            // A from h state (bf16 hi/lo)
            const int kh = k0 - II;
            #pragma unroll
            for (int i = 0; i < 8; ++i) {
                const int p = w * 8 + i;
                const int r = p * 4 + srow4;
                const int ls = sslot ^ (r & 15);
                const unsigned short* base = (ls & 1) ? Hlo_in : Hhi_in;
                gl_lds16(base + (size_t)(bBase + r) * HH + kh + (ls >> 1) * 8,
                         &smem[bufb + (unsigned)p * 1024u]);
            }
        } else {
            // A from fp32 x: reg-stage 32 floats/thread, split hi/lo, swizzled ds_write
            const int row = tid >> 1;                   // 0..63
            const int half = tid & 1;                   // which 32-float half
            const float* s = x + (size_t)(bBase + row) * xstride + k0 + half * 32;
            const int rs = row & 15;
            #pragma unroll
            for (int o2 = 0; o2 < 4; ++o2) {
                const float4 v0 = *(const float4*)(s + o2 * 8);
                const float4 v1 = *(const float4*)(s + o2 * 8 + 4);
                const float vv[8] = {v0.x, v0.y, v0.z, v0.w, v1.x, v1.y, v1.z, v1.w};
                bf16x8 hv, lv;
                #pragma unroll
                for (int e = 0; e < 8; ++e) {
                    const unsigned short hb = f2bf(vv[e]);
                    hv[e] = (short)hb;
                    lv[e] = (short)f2bf(vv[e] - bf2f(hb));
                }
                const int o = half * 4 + o2;            // global octet 0..7
                *(bf16x8*)&smem[bufb + row * 256 + (unsigned)(((2 * o) ^ rs) * 16)] = hv;
                *(bf16x8*)&smem[bufb + row * 256 + (unsigned)(((2 * o + 1) ^ rs) * 16)] = lv;
            }
        }
    };

    auto compute = [&](int buf) {
        const unsigned bufb = (unsigned)buf * 32768u;
        #pragma unroll
        for (int ks = 0; ks < 2; ++ks) {
            bf16x8 ah[4], al[4], bh[2], bl[2];
            #pragma unroll
            for (int mi = 0; mi < 4; ++mi) {
                ah[mi] = *(const bf16x8*)&smem[bufb + a_off[mi][ks][0]];
                al[mi] = *(const bf16x8*)&smem[bufb + a_off[mi][ks][1]];
            }
            #pragma unroll
            for (int ni = 0; ni < 2; ++ni) {
                bh[ni] = *(const bf16x8*)&smem[bufb + b_off[ni][ks][0]];
                bl[ni] = *(const bf16x8*)&smem[bufb + b_off[ni][ks][1]];
            }
            #pragma unroll
            for (int mi = 0; mi < 4; ++mi)
                #pragma unroll
                for (int ni = 0; ni < 2; ++ni) {
                    acc[mi][ni] = __builtin_amdgcn_mfma_f32_16x16x32_bf16(ah[mi], bh[ni], acc[mi][ni], 0, 0, 0);
                    acc[mi][ni] = __builtin_amdgcn_mfma_f32_16x16x32_bf16(ah[mi], bl[ni], acc[mi][ni], 0, 0, 0);
                    acc[mi][ni] = __builtin_amdgcn_mfma_f32_16x16x32_bf16(al[mi], bh[ni], acc[mi][ni], 0, 0, 0);
                }
        }
    };

    stage(0, 0);
    __syncthreads();
    #pragma unroll 1
    for (int c = 0; c < NCHV; ++c) {
        if (c + 1 < NCHV) stage(c + 1, (c + 1) & 1);  // prefetch before compute
        compute(c & 1);
        __syncthreads();
    }

    // ---- epilogue: gates -> LDS (f32, +bias), then per-unit float4 read ----
    float* glds = (float*)smem;                       // [64][68] f32 = 17408B
    #pragma unroll
    for (int ni = 0; ni < 2; ++ni) {
        const int col = w * 32 + ni * 16 + lr;
        const float bv = bsum[nBase + col];
        #pragma unroll
        for (int mi = 0; mi < 4; ++mi)
            #pragma unroll
            for (int r = 0; r < 4; ++r)
                glds[(mi * 16 + lg * 4 + r) * 68 + col] = acc[mi][ni][r] + bv;
    }
    __syncthreads();

    const int ju = tid & 15;                          // local unit (16 per tile)
    const int jglob = (nBase >> 2) + ju;
    #pragma unroll
    for (int ii = 0; ii < 8; ++ii) {
        const int brow = ii * 8 + (tid >> 4);
        const float4 g4 = *(const float4*)&glds[brow * 68 + ju * 4];  // i,f,g,o
        const size_t idx = (size_t)(bBase + brow) * HH + jglob;
        const float i_ = sig_(g4.x);
        const float f_ = sig_(g4.y);
        const float gg = tanhf(g4.z);
        const float o_ = sig_(g4.w);
        const float cn = f_ * cst[idx] + i_ * gg;
        cst[idx] = cn;
        const float hn = o_ * tanhf(cn);
        const unsigned short hh = f2bf(hn);
        Hhi_out[idx] = hh;
        Hlo_out[idx] = f2bf(hn - bf2f(hh));
        if (write_h32) h32[idx] = hn;
    }
}

// W reorder+split: W'[n'][k], n' = j*4+g, k = [Wih | Whh]; bsum = bih+bhh in n' order.
__global__ __launch_bounds__(128)
void convert_w(const float* __restrict__ Wih, const float* __restrict__ Whh,
               const float* __restrict__ bih, const float* __restrict__ bhh,
               unsigned short* __restrict__ Whi, unsigned short* __restrict__ Wlo,
               float* __restrict__ bsum)
{
    const int np = blockIdx.x;
    const int g = np & 3, j = np >> 2;
    const int n = g * HH + j;
    for (int k = threadIdx.x; k < KW; k += 128) {
        const float v = (k < II) ? Wih[(size_t)n * II + k] : Whh[(size_t)n * HH + (k - II)];
        const unsigned short h = f2bf(v);
        Whi[(size_t)np * KW + k] = h;
        Wlo[(size_t)np * KW + k] = f2bf(v - bf2f(h));
    }
    if (threadIdx.x == 0) bsum[np] = bih[n] + bhh[n];
}

// y = h @ fc_w^T + fc_b ; writes output slice AND next decoder input (fp32).
__global__ __launch_bounds__(512)
void fc_step_f32(const float* __restrict__ h, const float* __restrict__ fcw,
                 const float* __restrict__ fcb, float* __restrict__ outp,
                 float* __restrict__ xbuf)
{
    __shared__ float part[4][OO];
    const int tid = threadIdx.x;
    const int o  = tid & 127;
    const int ks = tid >> 7;
    const int b  = blockIdx.x;
    const float* hr = h + (size_t)b * HH + ks * 256;
    const float* wr = fcw + (size_t)o * HH + ks * 256;
    float s0 = 0.f, s1 = 0.f;
    #pragma unroll 4
    for (int k = 0; k < 256; k += 8) {
        const float4 hv0 = *(const float4*)&hr[k];
        const float4 wv0 = *(const float4*)&wr[k];
        const float4 hv1 = *(const float4*)&hr[k + 4];
        const float4 wv1 = *(const float4*)&wr[k + 4];
        s0 += hv0.x * wv0.x + hv0.y * wv0.y + hv0.z * wv0.z + hv0.w * wv0.w;
        s1 += hv1.x * wv1.x + hv1.y * wv1.y + hv1.z * wv1.z + hv1.w * wv1.w;
    }
    part[ks][o] = s0 + s1;
    __syncthreads();
    if (tid < OO) {
        const float y = part[0][tid] + part[1][tid] + part[2][tid] + part[3][tid] + fcb[tid];
        outp[(size_t)b * (TD * OO) + tid] = y;
        xbuf[(size_t)b * OO + tid] = y;
    }
}

extern "C" void kernel_launch(void* const* d_in, const int* in_sizes, int n_in,
                              void* d_out, int out_size, void* d_ws, size_t ws_size,
                              hipStream_t stream) {
    const float* enc   = (const float*)d_in[0];
    const float* Wih_e = (const float*)d_in[1];
    const float* Whh_e = (const float*)d_in[2];
    const float* bih_e = (const float*)d_in[3];
    const float* bhh_e = (const float*)d_in[4];
    const float* Wih_d = (const float*)d_in[5];
    const float* Whh_d = (const float*)d_in[6];
    const float* bih_d = (const float*)d_in[7];
    const float* bhh_d = (const float*)d_in[8];
    const float* fcw   = (const float*)d_in[9];
    const float* fcb   = (const float*)d_in[10];
    float* out = (float*)d_out;

    // Workspace layout. Zero region first: [c][Hhi0][Hlo0][xb]
    char* p = (char*)d_ws;
    float* c            = (float*)p;            p += (size_t)NB * HH * 4;
    unsigned short* Hhi0 = (unsigned short*)p;  p += (size_t)NB * HH * 2;
    unsigned short* Hlo0 = (unsigned short*)p;  p += (size_t)NB * HH * 2;
    float* xb           = (float*)p;            p += (size_t)NB * OO * 4;
    const size_t zbytes = (size_t)(p - (char*)d_ws);
    float* h32          = (float*)p;            p += (size_t)NB * HH * 4;
    unsigned short* Hhi1 = (unsigned short*)p;  p += (size_t)NB * HH * 2;
    unsigned short* Hlo1 = (unsigned short*)p;  p += (size_t)NB * HH * 2;
    unsigned short* Whi_e = (unsigned short*)p; p += (size_t)4 * HH * KW * 2;
    unsigned short* Wlo_e = (unsigned short*)p; p += (size_t)4 * HH * KW * 2;
    unsigned short* Whi_d = (unsigned short*)p; p += (size_t)4 * HH * KW * 2;
    unsigned short* Wlo_d = (unsigned short*)p; p += (size_t)4 * HH * KW * 2;
    float* bsum_e       = (float*)p;            p += (size_t)4 * HH * 4;
    float* bsum_d       = (float*)p;            p += (size_t)4 * HH * 4;

    convert_w<<<4 * HH, 128, 0, stream>>>(Wih_e, Whh_e, bih_e, bhh_e, Whi_e, Wlo_e, bsum_e);
    convert_w<<<4 * HH, 128, 0, stream>>>(Wih_d, Whh_d, bih_d, bhh_d, Whi_d, Wlo_d, bsum_d);
    hipMemsetAsync(d_ws, 0, zbytes, stream);

    const unsigned short *hi_in = Hhi0, *lo_in = Hlo0;
    unsigned short *hi_out = Hhi1, *lo_out = Hlo1;

    for (int t = 0; t < TT; ++t) {
        lstm_step_mfma<<<512, 128, 0, stream>>>(
            enc + (size_t)t * II, (long long)TT * II,
            Whi_e, Wlo_e, bsum_e, hi_in, lo_in, hi_out, lo_out, h32, 0, c);
        const unsigned short* th = hi_in; hi_in = hi_out; hi_out = (unsigned short*)th;
        const unsigned short* tl = lo_in; lo_in = lo_out; lo_out = (unsigned short*)tl;
    }
    for (int t = 0; t < TD; ++t) {
        lstm_step_mfma<<<512, 128, 0, stream>>>(
            xb, (long long)OO,
            Whi_d, Wlo_d, bsum_d, hi_in, lo_in, hi_out, lo_out, h32, 1, c);
        fc_step_f32<<<NB, 512, 0, stream>>>(h32, fcw, fcb, out + (size_t)t * OO, xb);
        const unsigned short* th = hi_in; hi_in = hi_out; hi_out = (unsigned short*)th;
        const unsigned short* tl = lo_in; lo_in = lo_out; lo_out = (unsigned short*)tl;
    }
}

// Round 6
// 10753.156 us; speedup vs baseline: 1.4792x; 1.4792x over previous
//
#include <hip/hip_runtime.h>
#include <math.h>

#define NB 512
#define TT 256
#define II 128
#define HH 1024
#define OO 128
#define TD 128
#define KC 128
#define NCHV 9          // (II+HH)/KC ; chunk 0 == x segment exactly
#define KW (II + HH)    // 1152

typedef __attribute__((ext_vector_type(8))) _Float16 f16x8;
typedef __attribute__((ext_vector_type(4))) float f32x4;

__device__ __forceinline__ float sig_(float x) { return 1.0f / (1.0f + expf(-x)); }

__device__ __forceinline__ void gl_lds16(const void* g, void* l) {
    __builtin_amdgcn_global_load_lds(
        (const __attribute__((address_space(1))) unsigned int*)g,
        (__attribute__((address_space(3))) unsigned int*)l, 16, 0, 0);
}

// One LSTM step, single-term fp16 MFMA.
// gates[b][n'] = sum_k A[b][k] * W'[n'][k], n' = j*4+g (gate-interleaved).
// A = [x (fp32->fp16 reg-staged, chunk 0) | h (fp16, chunks 1..8)], K = 1152.
// Grid 512 blocks (8 batch x 64 n-tiles, XCD-chunked), 256 thr = 4 waves (2x2 grid),
// block tile 64x64, wave tile 32x32, KC=128 double-buffered (2 x 32KB LDS), 2 blk/CU.
// LDS row = 256B = 16 slots x 16B (slot u = k-octet u); stored slot = u ^ (row & 15)
// -> conflict-free ds_read_b128 (rule #21: linear LDS dest, pre-swizzled global src).
__global__ __launch_bounds__(256, 2)
void lstm_step_mfma(const float* __restrict__ x, long long xstride,
                    const _Float16* __restrict__ Wf,
                    const float* __restrict__ bsum,
                    const _Float16* __restrict__ Hf_in,
                    _Float16* __restrict__ Hf_out,
                    float* __restrict__ h32, int write_h32,
                    float* __restrict__ cst)
{
    __shared__ __align__(16) unsigned char smem[65536];  // 2 buf x (A 16KB + B 16KB)

    const int tid = threadIdx.x;
    const int id  = blockIdx.x;
    const int xcd = id & 7;                 // hw round-robin -> XCD
    const int rest = id >> 3;
    const int nb  = rest & 7;
    const int bb  = rest >> 3;
    const int bBase = bb * 64;
    const int nBase = (xcd * 8 + nb) * 64;  // XCD's W slice L2-resident

    const int l  = tid & 63;
    const int w  = tid >> 6;                // wave 0..3
    const int wm = w & 1, wn = w >> 1;      // 2x2 wave grid
    const int lr = l & 15;
    const int lg = l >> 4;                  // k-octet within 32-k subtile

    // ds_read byte offsets: [frag][ks] ; ks = 32-k subtile 0..3 within the 128-k chunk
    int a_off[2][4], b_off[2][4];
    #pragma unroll
    for (int ks = 0; ks < 4; ++ks) {
        const int ls = ks * 4 + lg;         // logical k-octet 0..15
        #pragma unroll
        for (int mi = 0; mi < 2; ++mi) {
            const int arow = wm * 32 + mi * 16 + lr;
            a_off[mi][ks] = arow * 256 + ((ls ^ (arow & 15)) * 16);
            const int brow = wn * 32 + mi * 16 + lr;
            b_off[mi][ks] = 16384 + brow * 256 + ((ls ^ (brow & 15)) * 16);
        }
    }

    // gl_lds16 decode: instr p writes 1KB = 4 rows x 256B; lane l -> row p*4+(l>>4),
    // stored slot l&15; logical slot = (l&15) ^ (row&15)
    const int srow4 = l >> 4;
    const int sslot = l & 15;

    f32x4 acc[2][2];
    #pragma unroll
    for (int mi = 0; mi < 2; ++mi)
        #pragma unroll
        for (int ni = 0; ni < 2; ++ni)
            acc[mi][ni] = (f32x4){0.f, 0.f, 0.f, 0.f};

    auto stage = [&](int cc, int buf) {
        const unsigned bufb = (unsigned)buf * 32768u;
        const int k0 = cc * KC;
        // B from W' : 16 gl_lds16 per block (4 per wave) covering 64 rows x 256B
        #pragma unroll
        for (int i = 0; i < 4; ++i) {
            const int p = w * 4 + i;
            const int r = p * 4 + srow4;
            const int s = sslot ^ (r & 15);
            gl_lds16(Wf + (size_t)(nBase + r) * KW + k0 + s * 8,
                     &smem[bufb + 16384u + (unsigned)p * 1024u]);
        }
        if (cc >= 1) {
            // A from h state (fp16)
            const int kh = k0 - II;
            #pragma unroll
            for (int i = 0; i < 4; ++i) {
                const int p = w * 4 + i;
                const int r = p * 4 + srow4;
                const int s = sslot ^ (r & 15);
                gl_lds16(Hf_in + (size_t)(bBase + r) * HH + kh + s * 8,
                         &smem[bufb + (unsigned)p * 1024u]);
            }
        } else {
            // A from fp32 x (chunk 0 == k 0..127): reg-stage, cvt fp16, swizzled ds_write
            const int row = tid >> 2;               // 0..63
            const int q   = tid & 3;                // quarter: octets q*4 .. q*4+3
            const float* s = x + (size_t)(bBase + row) * xstride + q * 32;
            const int rs = row & 15;
            #pragma unroll
            for (int o2 = 0; o2 < 4; ++o2) {
                const float4 v0 = *(const float4*)(s + o2 * 8);
                const float4 v1 = *(const float4*)(s + o2 * 8 + 4);
                f16x8 hv;
                hv[0] = (_Float16)v0.x; hv[1] = (_Float16)v0.y;
                hv[2] = (_Float16)v0.z; hv[3] = (_Float16)v0.w;
                hv[4] = (_Float16)v1.x; hv[5] = (_Float16)v1.y;
                hv[6] = (_Float16)v1.z; hv[7] = (_Float16)v1.w;
                const int o = q * 4 + o2;           // logical octet 0..15
                *(f16x8*)&smem[bufb + row * 256 + (unsigned)((o ^ rs) * 16)] = hv;
            }
        }
    };

    auto compute = [&](int buf) {
        const unsigned bufb = (unsigned)buf * 32768u;
        #pragma unroll
        for (int ks = 0; ks < 4; ++ks) {
            f16x8 a[2], b[2];
            #pragma unroll
            for (int mi = 0; mi < 2; ++mi) {
                a[mi] = *(const f16x8*)&smem[bufb + a_off[mi][ks]];
                b[mi] = *(const f16x8*)&smem[bufb + b_off[mi][ks]];
            }
            #pragma unroll
            for (int mi = 0; mi < 2; ++mi)
                #pragma unroll
                for (int ni = 0; ni < 2; ++ni)
                    acc[mi][ni] = __builtin_amdgcn_mfma_f32_16x16x32_f16(a[mi], b[ni], acc[mi][ni], 0, 0, 0);
        }
    };

    stage(0, 0);
    __syncthreads();
    #pragma unroll 1
    for (int c = 0; c < NCHV; ++c) {
        if (c + 1 < NCHV) stage(c + 1, (c + 1) & 1);  // prefetch before compute
        compute(c & 1);
        __syncthreads();
    }

    // ---- epilogue: gates -> LDS (f32, +bias), then per-unit float4 read ----
    float* glds = (float*)smem;                       // [64][68] f32 = 17408B
    #pragma unroll
    for (int ni = 0; ni < 2; ++ni) {
        const int col = wn * 32 + ni * 16 + lr;
        const float bv = bsum[nBase + col];
        #pragma unroll
        for (int mi = 0; mi < 2; ++mi)
            #pragma unroll
            for (int r = 0; r < 4; ++r)
                glds[(wm * 32 + mi * 16 + lg * 4 + r) * 68 + col] = acc[mi][ni][r] + bv;
    }
    __syncthreads();

    const int ju = tid & 15;                          // local unit (16 per tile)
    const int jglob = (nBase >> 2) + ju;
    #pragma unroll
    for (int ii = 0; ii < 4; ++ii) {
        const int brow = ii * 16 + (tid >> 4);
        const float4 g4 = *(const float4*)&glds[brow * 68 + ju * 4];  // i,f,g,o
        const size_t idx = (size_t)(bBase + brow) * HH + jglob;
        const float i_ = sig_(g4.x);
        const float f_ = sig_(g4.y);
        const float gg = tanhf(g4.z);
        const float o_ = sig_(g4.w);
        const float cn = f_ * cst[idx] + i_ * gg;
        cst[idx] = cn;
        const float hn = o_ * tanhf(cn);
        Hf_out[idx] = (_Float16)hn;
        if (write_h32) h32[idx] = hn;
    }
}

// W reorder to fp16: W'[n'][k], n' = j*4+g, k = [Wih | Whh]; bsum = bih+bhh (n' order).
__global__ __launch_bounds__(128)
void convert_w(const float* __restrict__ Wih, const float* __restrict__ Whh,
               const float* __restrict__ bih, const float* __restrict__ bhh,
               _Float16* __restrict__ Wf, float* __restrict__ bsum)
{
    const int np = blockIdx.x;
    const int g = np & 3, j = np >> 2;
    const int n = g * HH + j;
    for (int k = threadIdx.x; k < KW; k += 128) {
        const float v = (k < II) ? Wih[(size_t)n * II + k] : Whh[(size_t)n * HH + (k - II)];
        Wf[(size_t)np * KW + k] = (_Float16)v;
    }
    if (threadIdx.x == 0) bsum[np] = bih[n] + bhh[n];
}

// y = h @ fc_w^T + fc_b (fp32) ; writes output slice AND next decoder input.
__global__ __launch_bounds__(512)
void fc_step_f32(const float* __restrict__ h, const float* __restrict__ fcw,
                 const float* __restrict__ fcb, float* __restrict__ outp,
                 float* __restrict__ xbuf)
{
    __shared__ float part[4][OO];
    const int tid = threadIdx.x;
    const int o  = tid & 127;
    const int ks = tid >> 7;
    const int b  = blockIdx.x;
    const float* hr = h + (size_t)b * HH + ks * 256;
    const float* wr = fcw + (size_t)o * HH + ks * 256;
    float s0 = 0.f, s1 = 0.f;
    #pragma unroll 4
    for (int k = 0; k < 256; k += 8) {
        const float4 hv0 = *(const float4*)&hr[k];
        const float4 wv0 = *(const float4*)&wr[k];
        const float4 hv1 = *(const float4*)&hr[k + 4];
        const float4 wv1 = *(const float4*)&wr[k + 4];
        s0 += hv0.x * wv0.x + hv0.y * wv0.y + hv0.z * wv0.z + hv0.w * wv0.w;
        s1 += hv1.x * wv1.x + hv1.y * wv1.y + hv1.z * wv1.z + hv1.w * wv1.w;
    }
    part[ks][o] = s0 + s1;
    __syncthreads();
    if (tid < OO) {
        const float y = part[0][tid] + part[1][tid] + part[2][tid] + part[3][tid] + fcb[tid];
        outp[(size_t)b * (TD * OO) + tid] = y;
        xbuf[(size_t)b * OO + tid] = y;
    }
}

extern "C" void kernel_launch(void* const* d_in, const int* in_sizes, int n_in,
                              void* d_out, int out_size, void* d_ws, size_t ws_size,
                              hipStream_t stream) {
    const float* enc   = (const float*)d_in[0];
    const float* Wih_e = (const float*)d_in[1];
    const float* Whh_e = (const float*)d_in[2];
    const float* bih_e = (const float*)d_in[3];
    const float* bhh_e = (const float*)d_in[4];
    const float* Wih_d = (const float*)d_in[5];
    const float* Whh_d = (const float*)d_in[6];
    const float* bih_d = (const float*)d_in[7];
    const float* bhh_d = (const float*)d_in[8];
    const float* fcw   = (const float*)d_in[9];
    const float* fcb   = (const float*)d_in[10];
    float* out = (float*)d_out;

    // Workspace layout. Zero region first: [c][Hf0][xb]
    char* p = (char*)d_ws;
    float* c          = (float*)p;        p += (size_t)NB * HH * 4;
    _Float16* Hf0     = (_Float16*)p;     p += (size_t)NB * HH * 2;
    float* xb         = (float*)p;        p += (size_t)NB * OO * 4;
    const size_t zbytes = (size_t)(p - (char*)d_ws);
    float* h32        = (float*)p;        p += (size_t)NB * HH * 4;
    _Float16* Hf1     = (_Float16*)p;     p += (size_t)NB * HH * 2;
    _Float16* Wf_e    = (_Float16*)p;     p += (size_t)4 * HH * KW * 2;
    _Float16* Wf_d    = (_Float16*)p;     p += (size_t)4 * HH * KW * 2;
    float* bsum_e     = (float*)p;        p += (size_t)4 * HH * 4;
    float* bsum_d     = (float*)p;        p += (size_t)4 * HH * 4;

    convert_w<<<4 * HH, 128, 0, stream>>>(Wih_e, Whh_e, bih_e, bhh_e, Wf_e, bsum_e);
    convert_w<<<4 * HH, 128, 0, stream>>>(Wih_d, Whh_d, bih_d, bhh_d, Wf_d, bsum_d);
    hipMemsetAsync(d_ws, 0, zbytes, stream);

    const _Float16* hin = Hf0;
    _Float16* hout = Hf1;

    for (int t = 0; t < TT; ++t) {
        lstm_step_mfma<<<512, 256, 0, stream>>>(
            enc + (size_t)t * II, (long long)TT * II,
            Wf_e, bsum_e, hin, hout, h32, 0, c);
        const _Float16* tmp = hin; hin = hout; hout = (_Float16*)tmp;
    }
    for (int t = 0; t < TD; ++t) {
        lstm_step_mfma<<<512, 256, 0, stream>>>(
            xb, (long long)OO,
            Wf_d, bsum_d, hin, hout, h32, 1, c);
        fc_step_f32<<<NB, 512, 0, stream>>>(h32, fcw, fcb, out + (size_t)t * OO, xb);
        const _Float16* tmp = hin; hin = hout; hout = (_Float16*)tmp;
    }
}